// Round 11
// baseline (727.899 us; speedup 1.0000x reference)
//
#include <hip/hip_runtime.h>
#include <hip/hip_cooperative_groups.h>
#include <math.h>

namespace cg = cooperative_groups;

#define B 16
#define N 4096
#define NPTS (B * N)   // 65536
#define NBK 2048       // knn grid blocks (128 per batch)
#define NBT 1024       // tail grid blocks (64 points/block, 64 per batch)
#define EPSF 1e-6f
#define S8(i) ((i) * 8)  // 64B-padded double slot

__device__ __forceinline__ float waveReduceSum(float v) {
#pragma unroll
    for (int m = 32; m > 0; m >>= 1) v += __shfl_xor(v, m, 64);
    return v;
}

__device__ __forceinline__ void leaky3(float px, float py, float pz,
                                       float dx, float dy, float dz, float s,
                                       float& ox, float& oy, float& oz) {
    float dotr = px * dx + py * dy + pz * dz;
    float dsq = dx * dx + dy * dy + dz * dz;
    float dot = s * dotr;
    float coef = (dot >= 0.f) ? 0.f : (dot / (dsq + EPSF));
    ox = s * px - coef * dx;
    oy = s * py - coef * dy;
    oz = s * pz - coef * dz;
}

// Batched stats: slot (b*2*cnt + i) = sum_i of batch b, (b*2*cnt + cnt + i) = sumsq.
__device__ __forceinline__ void mk_muisd_b(const double* st, int cnt, double M,
                                           float* smu, float* sisd) {
    const int i = threadIdx.x;
    if (i < cnt) {
        double s1 = 0.0, s2 = 0.0;
#pragma unroll
        for (int b = 0; b < B; ++b) {
            s1 += st[S8(b * 2 * cnt + i)];
            s2 += st[S8(b * 2 * cnt + cnt + i)];
        }
        double m = s1 / M;
        double v = s2 / M - m * m;
        smu[i] = (float)m;
        sisd[i] = (float)(1.0 / sqrt(v + 1e-5));
    }
}

// volatile variant for use after grid.sync (bypass stale cache lines)
__device__ __forceinline__ void mk_muisd_v(const double* st, int cnt, double M,
                                           float* smu, float* sisd) {
    const int i = threadIdx.x;
    if (i < cnt) {
        const volatile double* vst = (const volatile double*)st;
        double s1 = 0.0, s2 = 0.0;
#pragma unroll
        for (int b = 0; b < B; ++b) {
            s1 += vst[S8(b * 2 * cnt + i)];
            s2 += vst[S8(b * 2 * cnt + cnt + i)];
        }
        double m = s1 / M;
        double v = s2 / M - m * m;
        smu[i] = (float)m;
        sisd[i] = (float)(1.0 / sqrt(v + 1e-5));
    }
}

struct Feat {
    float cx, cy, cz, e0x, e0y, e0z, e2x, e2y, e2z;
};

__device__ __forceinline__ Feat make_feat(const float* __restrict__ pc,
                                          const int* __restrict__ nbr, int pid) {
    const int b = pid >> 12, n = pid & (N - 1);
    const float* base = pc + (size_t)b * (3 * N);
    Feat f;
    f.cx = base[3 * n];
    f.cy = base[3 * n + 1];
    f.cz = base[3 * n + 2];
    const int jn = nbr[pid];
    float nx = base[3 * jn], ny = base[3 * jn + 1], nz = base[3 * jn + 2];
    f.e0x = nx - f.cx;
    f.e0y = ny - f.cy;
    f.e0z = nz - f.cz;
    f.e2x = ny * f.cz - nz * f.cy;
    f.e2y = nz * f.cx - nx * f.cz;
    f.e2z = nx * f.cy - ny * f.cx;
    return f;
}

__device__ __forceinline__ void l0_channel(const Feat& f, float w0, float w1,
                                           float w2, float u0, float u1, float u2,
                                           float mu, float isd, float g, float bb,
                                           float& x0, float& x1, float& x2) {
    float pSx = w1 * f.cx, pSy = w1 * f.cy, pSz = w1 * f.cz;
    float nS = sqrtf(pSx * pSx + pSy * pSy + pSz * pSz) + EPSF;
    float sS = ((nS - mu) * isd * g + bb) / nS;
    float oSx, oSy, oSz;
    leaky3(pSx, pSy, pSz, u1 * f.cx, u1 * f.cy, u1 * f.cz, sS, oSx, oSy, oSz);
    float px = w0 * f.e0x + w1 * f.cx + w2 * f.e2x;
    float py = w0 * f.e0y + w1 * f.cy + w2 * f.e2y;
    float pz = w0 * f.e0z + w1 * f.cz + w2 * f.e2z;
    float dx = u0 * f.e0x + u1 * f.cx + u2 * f.e2x;
    float dy = u0 * f.e0y + u1 * f.cy + u2 * f.e2y;
    float dz = u0 * f.e0z + u1 * f.cz + u2 * f.e2z;
    float nN = sqrtf(px * px + py * py + pz * pz) + EPSF;
    float sN = ((nN - mu) * isd * g + bb) / nN;
    float oNx, oNy, oNz;
    leaky3(px, py, pz, dx, dy, dz, sN, oNx, oNy, oNz);
    x0 = 0.5f * (oSx + oNx);
    x1 = 0.5f * (oSy + oNy);
    x2 = 0.5f * (oSz + oNz);
}

// ---------------- K1: nearest-other (branch-free scan) + layer0 BN stats -----------
#define QW 8
__global__ __launch_bounds__(256) void k_knn(const float* __restrict__ pc,
                                             const float* __restrict__ Wf0,
                                             int* __restrict__ nbrbest,
                                             double* __restrict__ st0) {
    __shared__ float sx[N], sy[N], sz[N];
    __shared__ float ws0[63], sred[168];
    const int b = blockIdx.x >> 7;
    const int qblk = (blockIdx.x & 127) * 32;
    const float* base = pc + (size_t)b * (N * 3);
    for (int j = threadIdx.x; j < N; j += 256) {
        sx[j] = base[3 * j + 0];
        sy[j] = base[3 * j + 1];
        sz[j] = base[3 * j + 2];
    }
    if (threadIdx.x < 63) ws0[threadIdx.x] = Wf0[threadIdx.x];
    __syncthreads();
    const int wid = threadIdx.x >> 6, lane = threadIdx.x & 63;
    const int q0 = qblk + wid * QW;
    float qx[QW], qy[QW], qz[QW], bv[QW];
    int bi[QW], bq[QW];
#pragma unroll
    for (int q = 0; q < QW; ++q) {
        qx[q] = sx[q0 + q];
        qy[q] = sy[q0 + q];
        qz[q] = sz[q0 + q];
        bv[q] = -3.0e38f;
        bi[q] = 0;
    }
#pragma unroll 4
    for (int ch = 0; ch < N / 64; ++ch) {
        const int j = ch * 64 + lane;
        const float xd = sx[j], yd = sy[j], zd = sz[j];
        const float nr2h = -0.5f * (xd * xd + yd * yd + zd * zd);
#pragma unroll
        for (int q = 0; q < QW; ++q) {
            float pd = fmaf(qx[q], xd, fmaf(qy[q], yd, fmaf(qz[q], zd, nr2h)));
            bool upd = (pd > bv[q]) && (j != q0 + q);
            bv[q] = upd ? pd : bv[q];
            bi[q] = upd ? j : bi[q];
        }
    }
#pragma unroll
    for (int q = 0; q < QW; ++q) {
        float a0v = bv[q], a1v = -3.0e38f;
        int a0i = bi[q], a1i = 0x7fffffff;
#pragma unroll
        for (int m = 1; m < 64; m <<= 1) {
            float b0v = __shfl_xor(a0v, m, 64), b1v = __shfl_xor(a1v, m, 64);
            int b0i = __shfl_xor(a0i, m, 64), b1i = __shfl_xor(a1i, m, 64);
            bool bf = (b0v > a0v) || (b0v == a0v && b0i < a0i);
            float c0v = bf ? a0v : b0v;
            int c0i = bf ? a0i : b0i;
            float c1v = bf ? b1v : a1v;
            int c1i = bf ? b1i : a1i;
            a0v = bf ? b0v : a0v;
            a0i = bf ? b0i : a0i;
            bool cf = (c0v > c1v) || (c0v == c1v && c0i < c1i);
            a1v = cf ? c0v : c1v;
            a1i = cf ? c0i : c1i;
        }
        const int i0 = a0i, i1 = a1i;
        double dxa = (double)qx[q] - (double)sx[i0];
        double dya = (double)qy[q] - (double)sy[i0];
        double dza = (double)qz[q] - (double)sz[i0];
        double d0 = dxa * dxa + dya * dya + dza * dza;
        double dxb = (double)qx[q] - (double)sx[i1];
        double dyb = (double)qy[q] - (double)sy[i1];
        double dzb = (double)qz[q] - (double)sz[i1];
        double d1 = dxb * dxb + dyb * dyb + dzb * dzb;
        bool take1 = (d1 < d0) || (d1 == d0 && i1 < i0);
        int best = take1 ? i1 : i0;
        bq[q] = best;
        if (lane == 0) nbrbest[(size_t)b * N + q0 + q] = best;
    }
    if (lane < 21) {
        float s1 = 0.f, s2 = 0.f;
        const float w0 = ws0[3 * lane], w1 = ws0[3 * lane + 1], w2 = ws0[3 * lane + 2];
#pragma unroll
        for (int q = 0; q < QW; ++q) {
            const int sq = q0 + q, jn = bq[q];
            const float cx = sx[sq], cy = sy[sq], cz = sz[sq];
            const float nx = sx[jn], ny = sy[jn], nz = sz[jn];
            const float e0x = nx - cx, e0y = ny - cy, e0z = nz - cz;
            const float e2x = ny * cz - nz * cy;
            const float e2y = nz * cx - nx * cz;
            const float e2z = nx * cy - ny * cx;
            float pSx = w1 * cx, pSy = w1 * cy, pSz = w1 * cz;
            float nS = sqrtf(pSx * pSx + pSy * pSy + pSz * pSz) + EPSF;
            float px = w0 * e0x + w1 * cx + w2 * e2x;
            float py = w0 * e0y + w1 * cy + w2 * e2y;
            float pz = w0 * e0z + w1 * cz + w2 * e2z;
            float nN = sqrtf(px * px + py * py + pz * pz) + EPSF;
            s1 += nS + nN;
            s2 += nS * nS + nN * nN;
        }
        sred[wid * 42 + lane] = s1;
        sred[wid * 42 + 21 + lane] = s2;
    }
    __syncthreads();
    if (threadIdx.x < 42) {
        float p = sred[threadIdx.x] + sred[42 + threadIdx.x] +
                  sred[84 + threadIdx.x] + sred[126 + threadIdx.x];
        atomicAdd(&st0[S8(b * 42 + threadIdx.x)], (double)p);
    }
}

// ---------------- K2 (primary): cooperative mega-tail -------------------------------
// 1024 blocks x 256 threads; each block keeps its 64 points' 63 features in LDS
// across all stages. Stats flow via per-batch global slots + grid.sync.
__global__ __launch_bounds__(256, 4) void k_mega(
    const float* __restrict__ pc, const int* __restrict__ nbr,
    const float* __restrict__ Wf0, const float* __restrict__ Wd0,
    const float* __restrict__ g0, const float* __restrict__ b0,
    const float* __restrict__ Wf1, const float* __restrict__ Wd1,
    const float* __restrict__ g1, const float* __restrict__ b1,
    const float* __restrict__ gbn1, const float* __restrict__ bbn1,
    const float* __restrict__ Wf2, const float* __restrict__ Wd2,
    const float* __restrict__ g2, const float* __restrict__ b2,
    const double* __restrict__ st0, double* __restrict__ st1,
    double* __restrict__ stB, double* __restrict__ st2,
    double* __restrict__ acc, float* __restrict__ out) {
    __shared__ float xs[63 * 64];
    __shared__ float wf0[63], wd0[63], wf1[441], wd1[441], wf2[63], wd2[63];
    __shared__ float g0s[21], b0s[21], g1s[21], b1s[21], gBs[21], bBs[21], g2s[3], b2s[3];
    __shared__ float mu0[21], isd0[21], mu1[21], isd1[21], muB[21], isdB[21], mu2[3], isd2[3];
    cg::grid_group grid = cg::this_grid();
    const int lane = threadIdx.x & 63, grp = threadIdx.x >> 6;
    const int pid = blockIdx.x * 64 + lane;
    const int bb = blockIdx.x >> 6;
    const int cbase = grp * 6;

    if (threadIdx.x < 63) {
        wf0[threadIdx.x] = Wf0[threadIdx.x];
        wd0[threadIdx.x] = Wd0[threadIdx.x];
        wf2[threadIdx.x] = Wf2[threadIdx.x];
        wd2[threadIdx.x] = Wd2[threadIdx.x];
    }
    for (int i = threadIdx.x; i < 441; i += 256) {
        wf1[i] = Wf1[i];
        wd1[i] = Wd1[i];
    }
    if (threadIdx.x < 21) {
        g0s[threadIdx.x] = g0[threadIdx.x];
        b0s[threadIdx.x] = b0[threadIdx.x];
        g1s[threadIdx.x] = g1[threadIdx.x];
        b1s[threadIdx.x] = b1[threadIdx.x];
        gBs[threadIdx.x] = gbn1[threadIdx.x];
        bBs[threadIdx.x] = bbn1[threadIdx.x];
    }
    if (threadIdx.x < 3) {
        g2s[threadIdx.x] = g2[threadIdx.x];
        b2s[threadIdx.x] = b2[threadIdx.x];
    }
    mk_muisd_b(st0, 21, (double)NPTS * 2.0, mu0, isd0);  // st0 from prior kernel
    __syncthreads();

    // ---- Stage A: layer0 apply -> xs ----
    {
        Feat f = make_feat(pc, nbr, pid);
#pragma unroll
        for (int k = 0; k < 6; ++k) {
            const int c = cbase + k;
            if (c >= 21) break;
            float x0, x1, x2;
            l0_channel(f, wf0[3 * c], wf0[3 * c + 1], wf0[3 * c + 2],
                       wd0[3 * c], wd0[3 * c + 1], wd0[3 * c + 2],
                       mu0[c], isd0[c], g0s[c], b0s[c], x0, x1, x2);
            xs[(3 * c + 0) * 64 + lane] = x0;
            xs[(3 * c + 1) * 64 + lane] = x1;
            xs[(3 * c + 2) * 64 + lane] = x2;
        }
    }
    __syncthreads();
    // ---- Stage A2: layer1 BN stats (j-outer, 18 accumulators) ----
    {
        float a0[6], a1[6], a2[6];
#pragma unroll
        for (int k = 0; k < 6; ++k) { a0[k] = 0.f; a1[k] = 0.f; a2[k] = 0.f; }
        for (int j = 0; j < 21; ++j) {
            float x0 = xs[(3 * j + 0) * 64 + lane];
            float x1 = xs[(3 * j + 1) * 64 + lane];
            float x2 = xs[(3 * j + 2) * 64 + lane];
#pragma unroll
            for (int k = 0; k < 6; ++k) {
                int cc = cbase + k;
                cc = cc < 21 ? cc : 20;
                float w = wf1[cc * 21 + j];
                a0[k] = fmaf(w, x0, a0[k]);
                a1[k] = fmaf(w, x1, a1[k]);
                a2[k] = fmaf(w, x2, a2[k]);
            }
        }
#pragma unroll
        for (int k = 0; k < 6; ++k) {
            const int c = cbase + k;
            if (c >= 21) break;
            float nn = sqrtf(a0[k] * a0[k] + a1[k] * a1[k] + a2[k] * a2[k]) + EPSF;
            float r1 = waveReduceSum(nn);
            float r2 = waveReduceSum(nn * nn);
            if (lane == 0) {
                atomicAdd(&st1[S8(bb * 42 + c)], (double)r1);
                atomicAdd(&st1[S8(bb * 42 + 21 + c)], (double)r2);
            }
        }
    }
    grid.sync();

    // ---- Stage B: layer1 apply (in LDS) + bn1 stats ----
    mk_muisd_v(st1, 21, (double)NPTS, mu1, isd1);
    __syncthreads();
    {
        float p0[6], p1[6], p2[6], q0[6], q1[6], q2[6];
#pragma unroll
        for (int k = 0; k < 6; ++k) {
            p0[k] = 0.f; p1[k] = 0.f; p2[k] = 0.f;
            q0[k] = 0.f; q1[k] = 0.f; q2[k] = 0.f;
        }
        for (int j = 0; j < 21; ++j) {
            float x0 = xs[(3 * j + 0) * 64 + lane];
            float x1 = xs[(3 * j + 1) * 64 + lane];
            float x2 = xs[(3 * j + 2) * 64 + lane];
#pragma unroll
            for (int k = 0; k < 6; ++k) {
                int cc = cbase + k;
                cc = cc < 21 ? cc : 20;
                float w = wf1[cc * 21 + j], u = wd1[cc * 21 + j];
                p0[k] = fmaf(w, x0, p0[k]);
                p1[k] = fmaf(w, x1, p1[k]);
                p2[k] = fmaf(w, x2, p2[k]);
                q0[k] = fmaf(u, x0, q0[k]);
                q1[k] = fmaf(u, x1, q1[k]);
                q2[k] = fmaf(u, x2, q2[k]);
            }
        }
        float sn1[6], sn2[6];
#pragma unroll
        for (int k = 0; k < 6; ++k) {
            int cc = cbase + k;
            cc = cc < 21 ? cc : 20;
            float nn = sqrtf(p0[k] * p0[k] + p1[k] * p1[k] + p2[k] * p2[k]) + EPSF;
            float s = ((nn - mu1[cc]) * isd1[cc] * g1s[cc] + b1s[cc]) / nn;
            float ox, oy, oz;
            leaky3(p0[k], p1[k], p2[k], q0[k], q1[k], q2[k], s, ox, oy, oz);
            p0[k] = ox; p1[k] = oy; p2[k] = oz;
            float on = sqrtf(ox * ox + oy * oy + oz * oz) + EPSF;
            sn1[k] = on;
            sn2[k] = on * on;
        }
        __syncthreads();  // all xs reads done before overwrite
#pragma unroll
        for (int k = 0; k < 6; ++k) {
            const int c = cbase + k;
            if (c >= 21) break;
            xs[(3 * c + 0) * 64 + lane] = p0[k];
            xs[(3 * c + 1) * 64 + lane] = p1[k];
            xs[(3 * c + 2) * 64 + lane] = p2[k];
            float r1 = waveReduceSum(sn1[k]);
            float r2 = waveReduceSum(sn2[k]);
            if (lane == 0) {
                atomicAdd(&stB[S8(bb * 42 + c)], (double)r1);
                atomicAdd(&stB[S8(bb * 42 + 21 + c)], (double)r2);
            }
        }
    }
    grid.sync();

    // ---- Stage C: bn1 apply in place + layer2 BN stats ----
    mk_muisd_v(stB, 21, (double)NPTS, muB, isdB);
    __syncthreads();
#pragma unroll
    for (int k = 0; k < 6; ++k) {
        const int c = cbase + k;
        if (c >= 21) break;
        float y0 = xs[(3 * c + 0) * 64 + lane];
        float y1 = xs[(3 * c + 1) * 64 + lane];
        float y2 = xs[(3 * c + 2) * 64 + lane];
        float nn = sqrtf(y0 * y0 + y1 * y1 + y2 * y2) + EPSF;
        float sc = ((nn - muB[c]) * isdB[c] * gBs[c] + bBs[c]) / nn;
        xs[(3 * c + 0) * 64 + lane] = sc * y0;
        xs[(3 * c + 1) * 64 + lane] = sc * y1;
        xs[(3 * c + 2) * 64 + lane] = sc * y2;
    }
    __syncthreads();
    if (grp < 3) {
        float p0 = 0.f, p1 = 0.f, p2 = 0.f;
        for (int j = 0; j < 21; ++j) {
            float w = wf2[grp * 21 + j];
            p0 = fmaf(w, xs[(3 * j + 0) * 64 + lane], p0);
            p1 = fmaf(w, xs[(3 * j + 1) * 64 + lane], p1);
            p2 = fmaf(w, xs[(3 * j + 2) * 64 + lane], p2);
        }
        float nn = sqrtf(p0 * p0 + p1 * p1 + p2 * p2) + EPSF;
        float r1 = waveReduceSum(nn);
        float r2 = waveReduceSum(nn * nn);
        if (lane == 0) {
            atomicAdd(&st2[S8(bb * 6 + grp)], (double)r1);
            atomicAdd(&st2[S8(bb * 6 + 3 + grp)], (double)r2);
        }
    }
    grid.sync();

    // ---- Stage D: layer2 apply + per-batch reduce ----
    mk_muisd_v(st2, 3, (double)NPTS, mu2, isd2);
    __syncthreads();
    if (grp < 3) {
        float p0 = 0.f, p1 = 0.f, p2 = 0.f, d0 = 0.f, d1 = 0.f, d2 = 0.f;
        for (int j = 0; j < 21; ++j) {
            float z0 = xs[(3 * j + 0) * 64 + lane];
            float z1 = xs[(3 * j + 1) * 64 + lane];
            float z2 = xs[(3 * j + 2) * 64 + lane];
            float w = wf2[grp * 21 + j], u = wd2[grp * 21 + j];
            p0 = fmaf(w, z0, p0);
            p1 = fmaf(w, z1, p1);
            p2 = fmaf(w, z2, p2);
            d0 = fmaf(u, z0, d0);
            d1 = fmaf(u, z1, d1);
            d2 = fmaf(u, z2, d2);
        }
        float nn = sqrtf(p0 * p0 + p1 * p1 + p2 * p2) + EPSF;
        float s = ((nn - mu2[grp]) * isd2[grp] * g2s[grp] + b2s[grp]) / nn;
        float ox, oy, oz;
        leaky3(p0, p1, p2, d0, d1, d2, s, ox, oy, oz);
        float rx = waveReduceSum(ox);
        float ry = waveReduceSum(oy);
        float rz = waveReduceSum(oz);
        if (lane == 0) {
            atomicAdd(&acc[S8(bb * 9 + grp * 3 + 0)], (double)rx);
            atomicAdd(&acc[S8(bb * 9 + grp * 3 + 1)], (double)ry);
            atomicAdd(&acc[S8(bb * 9 + grp * 3 + 2)], (double)rz);
        }
    }
    grid.sync();
    if (blockIdx.x == 0 && threadIdx.x < B * 9) {
        const volatile double* va = (const volatile double*)acc;
        out[threadIdx.x] = (float)(va[S8(threadIdx.x)] * (1.0 / (double)N));
    }
}

// ================= FALLBACK PATH (round-10 proven tail, used if coop launch fails) ==
__global__ __launch_bounds__(256) void k_l0st1(
    const float* __restrict__ pc, const int* __restrict__ nbr,
    const float* __restrict__ Wf0, const float* __restrict__ Wd0,
    const float* __restrict__ g0, const float* __restrict__ b0,
    const float* __restrict__ Wf1, const double* __restrict__ st0,
    float* __restrict__ xbuf, double* __restrict__ st1) {
    __shared__ float wf0[63], wd0[63], wf1[441], gg[21], bbs[21], mu[21], isd[21];
    __shared__ float xs[63 * 64];
    if (threadIdx.x < 63) {
        wf0[threadIdx.x] = Wf0[threadIdx.x];
        wd0[threadIdx.x] = Wd0[threadIdx.x];
    }
    for (int i = threadIdx.x; i < 441; i += 256) wf1[i] = Wf1[i];
    if (threadIdx.x < 21) {
        gg[threadIdx.x] = g0[threadIdx.x];
        bbs[threadIdx.x] = b0[threadIdx.x];
    }
    mk_muisd_b(st0, 21, (double)NPTS * 2.0, mu, isd);
    __syncthreads();
    const int lane = threadIdx.x & 63, grp = threadIdx.x >> 6;
    const int pid = blockIdx.x * 64 + lane;
    const int bb = blockIdx.x >> 6;
    Feat f = make_feat(pc, nbr, pid);
    const int cbase = grp * 6;
#pragma unroll
    for (int k = 0; k < 6; ++k) {
        const int c = cbase + k;
        if (c >= 21) break;
        float x0, x1, x2;
        l0_channel(f, wf0[3 * c], wf0[3 * c + 1], wf0[3 * c + 2],
                   wd0[3 * c], wd0[3 * c + 1], wd0[3 * c + 2],
                   mu[c], isd[c], gg[c], bbs[c], x0, x1, x2);
        xs[(3 * c + 0) * 64 + lane] = x0;
        xs[(3 * c + 1) * 64 + lane] = x1;
        xs[(3 * c + 2) * 64 + lane] = x2;
        xbuf[(size_t)(3 * c + 0) * NPTS + pid] = x0;
        xbuf[(size_t)(3 * c + 1) * NPTS + pid] = x1;
        xbuf[(size_t)(3 * c + 2) * NPTS + pid] = x2;
    }
    __syncthreads();
    float xl[63];
#pragma unroll
    for (int ff = 0; ff < 63; ++ff) xl[ff] = xs[ff * 64 + lane];
#pragma unroll
    for (int k = 0; k < 6; ++k) {
        const int c = cbase + k;
        if (c >= 21) break;
        float p0 = 0.f, p1 = 0.f, p2 = 0.f;
#pragma unroll
        for (int j = 0; j < 21; ++j) {
            float w = wf1[c * 21 + j];
            p0 = fmaf(w, xl[3 * j + 0], p0);
            p1 = fmaf(w, xl[3 * j + 1], p1);
            p2 = fmaf(w, xl[3 * j + 2], p2);
        }
        float nn = sqrtf(p0 * p0 + p1 * p1 + p2 * p2) + EPSF;
        float r1 = waveReduceSum(nn);
        float r2 = waveReduceSum(nn * nn);
        if (lane == 0) {
            atomicAdd(&st1[S8(bb * 42 + c)], (double)r1);
            atomicAdd(&st1[S8(bb * 42 + 21 + c)], (double)r2);
        }
    }
}

__global__ __launch_bounds__(256) void k_l1stB(
    float* __restrict__ xbuf, const float* __restrict__ Wf1,
    const float* __restrict__ Wd1, const float* __restrict__ g1,
    const float* __restrict__ b1, const double* __restrict__ st1,
    double* __restrict__ stB) {
    __shared__ float wf1[441], wd1[441], gg[21], bbs[21], mu[21], isd[21];
    for (int i = threadIdx.x; i < 441; i += 256) {
        wf1[i] = Wf1[i];
        wd1[i] = Wd1[i];
    }
    if (threadIdx.x < 21) {
        gg[threadIdx.x] = g1[threadIdx.x];
        bbs[threadIdx.x] = b1[threadIdx.x];
    }
    mk_muisd_b(st1, 21, (double)NPTS, mu, isd);
    __syncthreads();
    const int lane = threadIdx.x & 63, grp = threadIdx.x >> 6;
    const int pid = blockIdx.x * 64 + lane;
    const int bb = blockIdx.x >> 6;
    float xl[63];
#pragma unroll
    for (int ff = 0; ff < 63; ++ff) xl[ff] = xbuf[(size_t)ff * NPTS + pid];
    __syncthreads();
    const int cbase = grp * 6;
#pragma unroll
    for (int k = 0; k < 6; ++k) {
        const int c = cbase + k;
        if (c >= 21) break;
        float p0 = 0.f, p1 = 0.f, p2 = 0.f, d0 = 0.f, d1 = 0.f, d2 = 0.f;
#pragma unroll
        for (int j = 0; j < 21; ++j) {
            float w = wf1[c * 21 + j], u = wd1[c * 21 + j];
            p0 = fmaf(w, xl[3 * j + 0], p0);
            p1 = fmaf(w, xl[3 * j + 1], p1);
            p2 = fmaf(w, xl[3 * j + 2], p2);
            d0 = fmaf(u, xl[3 * j + 0], d0);
            d1 = fmaf(u, xl[3 * j + 1], d1);
            d2 = fmaf(u, xl[3 * j + 2], d2);
        }
        float nn = sqrtf(p0 * p0 + p1 * p1 + p2 * p2) + EPSF;
        float s = ((nn - mu[c]) * isd[c] * gg[c] + bbs[c]) / nn;
        float ox, oy, oz;
        leaky3(p0, p1, p2, d0, d1, d2, s, ox, oy, oz);
        xbuf[(size_t)(3 * c + 0) * NPTS + pid] = ox;
        xbuf[(size_t)(3 * c + 1) * NPTS + pid] = oy;
        xbuf[(size_t)(3 * c + 2) * NPTS + pid] = oz;
        float on = sqrtf(ox * ox + oy * oy + oz * oz) + EPSF;
        float r1 = waveReduceSum(on);
        float r2 = waveReduceSum(on * on);
        if (lane == 0) {
            atomicAdd(&stB[S8(bb * 42 + c)], (double)r1);
            atomicAdd(&stB[S8(bb * 42 + 21 + c)], (double)r2);
        }
    }
}

__global__ __launch_bounds__(256) void k_bn1st2(
    const float* __restrict__ xbuf, const float* __restrict__ gbn,
    const float* __restrict__ bbn, const float* __restrict__ Wf2,
    const double* __restrict__ stB, double* __restrict__ st2) {
    __shared__ float wf2[63], gg[21], bbs[21], mu[21], isd[21];
    __shared__ float zs[63 * 64];
    if (threadIdx.x < 63) wf2[threadIdx.x] = Wf2[threadIdx.x];
    if (threadIdx.x < 21) {
        gg[threadIdx.x] = gbn[threadIdx.x];
        bbs[threadIdx.x] = bbn[threadIdx.x];
    }
    mk_muisd_b(stB, 21, (double)NPTS, mu, isd);
    __syncthreads();
    const int lane = threadIdx.x & 63, grp = threadIdx.x >> 6;
    const int pid = blockIdx.x * 64 + lane;
    const int bb = blockIdx.x >> 6;
    const int cbase = grp * 6;
#pragma unroll
    for (int k = 0; k < 6; ++k) {
        const int c = cbase + k;
        if (c >= 21) break;
        float y0 = xbuf[(size_t)(3 * c + 0) * NPTS + pid];
        float y1 = xbuf[(size_t)(3 * c + 1) * NPTS + pid];
        float y2 = xbuf[(size_t)(3 * c + 2) * NPTS + pid];
        float nn = sqrtf(y0 * y0 + y1 * y1 + y2 * y2) + EPSF;
        float sc = ((nn - mu[c]) * isd[c] * gg[c] + bbs[c]) / nn;
        zs[(3 * c + 0) * 64 + lane] = sc * y0;
        zs[(3 * c + 1) * 64 + lane] = sc * y1;
        zs[(3 * c + 2) * 64 + lane] = sc * y2;
    }
    __syncthreads();
    if (grp < 3) {
        float p0 = 0.f, p1 = 0.f, p2 = 0.f;
#pragma unroll
        for (int j = 0; j < 21; ++j) {
            float w = wf2[grp * 21 + j];
            p0 = fmaf(w, zs[(3 * j + 0) * 64 + lane], p0);
            p1 = fmaf(w, zs[(3 * j + 1) * 64 + lane], p1);
            p2 = fmaf(w, zs[(3 * j + 2) * 64 + lane], p2);
        }
        float nn = sqrtf(p0 * p0 + p1 * p1 + p2 * p2) + EPSF;
        float r1 = waveReduceSum(nn);
        float r2 = waveReduceSum(nn * nn);
        if (lane == 0) {
            atomicAdd(&st2[S8(bb * 6 + grp)], (double)r1);
            atomicAdd(&st2[S8(bb * 6 + 3 + grp)], (double)r2);
        }
    }
}

__global__ __launch_bounds__(256) void k_acc(
    const float* __restrict__ xbuf, const float* __restrict__ gbn,
    const float* __restrict__ bbn, const float* __restrict__ Wf2,
    const float* __restrict__ Wd2, const float* __restrict__ g2,
    const float* __restrict__ b2, const double* __restrict__ stB,
    const double* __restrict__ st2, double* __restrict__ acc) {
    __shared__ float wf2[63], wd2[63], gg[3], bbs[3];
    __shared__ float muB[21], isdB[21], gB[21], bB[21], mu2[3], isd2[3];
    if (threadIdx.x < 63) {
        wf2[threadIdx.x] = Wf2[threadIdx.x];
        wd2[threadIdx.x] = Wd2[threadIdx.x];
    }
    if (threadIdx.x < 21) {
        gB[threadIdx.x] = gbn[threadIdx.x];
        bB[threadIdx.x] = bbn[threadIdx.x];
    }
    if (threadIdx.x < 3) {
        gg[threadIdx.x] = g2[threadIdx.x];
        bbs[threadIdx.x] = b2[threadIdx.x];
    }
    mk_muisd_b(stB, 21, (double)NPTS, muB, isdB);
    mk_muisd_b(st2, 3, (double)NPTS, mu2, isd2);
    __syncthreads();
    const int lane = threadIdx.x & 63, grp = threadIdx.x >> 6;
    if (grp >= 3) return;
    const int pid = blockIdx.x * 64 + lane;
    const int bb = pid >> 12;
    float p0 = 0.f, p1 = 0.f, p2 = 0.f, d0 = 0.f, d1 = 0.f, d2 = 0.f;
#pragma unroll
    for (int j = 0; j < 21; ++j) {
        float y0 = xbuf[(size_t)(3 * j + 0) * NPTS + pid];
        float y1 = xbuf[(size_t)(3 * j + 1) * NPTS + pid];
        float y2 = xbuf[(size_t)(3 * j + 2) * NPTS + pid];
        float nn = sqrtf(y0 * y0 + y1 * y1 + y2 * y2) + EPSF;
        float sc = ((nn - muB[j]) * isdB[j] * gB[j] + bB[j]) / nn;
        float z0 = sc * y0, z1 = sc * y1, z2 = sc * y2;
        float w = wf2[grp * 21 + j], u = wd2[grp * 21 + j];
        p0 = fmaf(w, z0, p0);
        p1 = fmaf(w, z1, p1);
        p2 = fmaf(w, z2, p2);
        d0 = fmaf(u, z0, d0);
        d1 = fmaf(u, z1, d1);
        d2 = fmaf(u, z2, d2);
    }
    float nn = sqrtf(p0 * p0 + p1 * p1 + p2 * p2) + EPSF;
    float s = ((nn - mu2[grp]) * isd2[grp] * gg[grp] + bbs[grp]) / nn;
    float ox, oy, oz;
    leaky3(p0, p1, p2, d0, d1, d2, s, ox, oy, oz);
    float rx = waveReduceSum(ox);
    float ry = waveReduceSum(oy);
    float rz = waveReduceSum(oz);
    if (lane == 0) {
        atomicAdd(&acc[S8(bb * 9 + grp * 3 + 0)], (double)rx);
        atomicAdd(&acc[S8(bb * 9 + grp * 3 + 1)], (double)ry);
        atomicAdd(&acc[S8(bb * 9 + grp * 3 + 2)], (double)rz);
    }
}

__global__ void k_fin(const double* __restrict__ acc, float* __restrict__ out) {
    if (threadIdx.x < B * 9)
        out[threadIdx.x] = (float)(acc[S8(threadIdx.x)] * (1.0 / (double)N));
}

extern "C" void kernel_launch(void* const* d_in, const int* in_sizes, int n_in,
                              void* d_out, int out_size, void* d_ws, size_t ws_size,
                              hipStream_t stream) {
    const float* pc = (const float*)d_in[0];
    const float* Wf0 = (const float*)d_in[1];
    const float* Wd0 = (const float*)d_in[2];
    const float* g0 = (const float*)d_in[3];
    const float* b0 = (const float*)d_in[4];
    const float* Wf1 = (const float*)d_in[5];
    const float* Wd1 = (const float*)d_in[6];
    const float* g1 = (const float*)d_in[7];
    const float* b1 = (const float*)d_in[8];
    const float* gbn1 = (const float*)d_in[9];
    const float* bbn1 = (const float*)d_in[10];
    const float* Wf2 = (const float*)d_in[11];
    const float* Wd2 = (const float*)d_in[12];
    const float* g2 = (const float*)d_in[13];
    const float* b2 = (const float*)d_in[14];
    float* out = (float*)d_out;

    char* ws = (char*)d_ws;
    double* gws = (double*)ws;
    double* st0 = gws;                // slots [0, 672)
    double* st1 = gws + S8(672);      // [672, 1344)
    double* stB = gws + S8(1344);     // [1344, 2016)
    double* st2 = gws + S8(2016);     // [2016, 2112)
    double* acc = gws + S8(2112);     // [2112, 2256)  -> 144384 B
    int* nbrbest = (int*)(ws + 262144);   // 256 KB
    float* xbuf = (float*)(ws + 524288);  // 63*NPTS f32 = 16.5 MB (fallback only)

    hipMemsetAsync(d_ws, 0, 144384, stream);

    k_knn<<<NBK, 256, 0, stream>>>(pc, Wf0, nbrbest, st0);

    const int* nbrc = nbrbest;
    const double* st0c = st0;
    void* args[] = {(void*)&pc, (void*)&nbrc,
                    (void*)&Wf0, (void*)&Wd0, (void*)&g0, (void*)&b0,
                    (void*)&Wf1, (void*)&Wd1, (void*)&g1, (void*)&b1,
                    (void*)&gbn1, (void*)&bbn1,
                    (void*)&Wf2, (void*)&Wd2, (void*)&g2, (void*)&b2,
                    (void*)&st0c, (void*)&st1, (void*)&stB, (void*)&st2,
                    (void*)&acc, (void*)&out};
    hipError_t e = hipLaunchCooperativeKernel((void*)k_mega, dim3(NBT), dim3(256),
                                              args, 0, stream);
    if (e != hipSuccess) {
        // fallback: proven round-10 multi-kernel tail
        k_l0st1<<<NBT, 256, 0, stream>>>(pc, nbrbest, Wf0, Wd0, g0, b0, Wf1, st0,
                                         xbuf, st1);
        k_l1stB<<<NBT, 256, 0, stream>>>(xbuf, Wf1, Wd1, g1, b1, st1, stB);
        k_bn1st2<<<NBT, 256, 0, stream>>>(xbuf, gbn1, bbn1, Wf2, stB, st2);
        k_acc<<<NBT, 256, 0, stream>>>(xbuf, gbn1, bbn1, Wf2, Wd2, g2, b2, stB,
                                       st2, acc);
        k_fin<<<1, 256, 0, stream>>>(acc, out);
    }
}

// Round 13
// 422.075 us; speedup vs baseline: 1.7246x; 1.7246x over previous
//
#include <hip/hip_runtime.h>
#include <hip/hip_cooperative_groups.h>
#include <math.h>

namespace cg = cooperative_groups;

#define B 16
#define N 4096
#define NPTS (B * N)   // 65536
#define NBK 2048       // knn grid blocks (128 per batch)
#define NBT 1024       // point tiles (64 points each)
#define MGB 512        // mega grid blocks (2 tiles per block)
#define EPSF 1e-6f
#define S8(i) ((i) * 8)  // 64B-padded double slot

__device__ __forceinline__ float waveReduceSum(float v) {
#pragma unroll
    for (int m = 32; m > 0; m >>= 1) v += __shfl_xor(v, m, 64);
    return v;
}

__device__ __forceinline__ void leaky3(float px, float py, float pz,
                                       float dx, float dy, float dz, float s,
                                       float& ox, float& oy, float& oz) {
    float dotr = px * dx + py * dy + pz * dz;
    float dsq = dx * dx + dy * dy + dz * dz;
    float dot = s * dotr;
    float coef = (dot >= 0.f) ? 0.f : (dot / (dsq + EPSF));
    ox = s * px - coef * dx;
    oy = s * py - coef * dy;
    oz = s * pz - coef * dz;
}

// Batched stats: slot (b*2*cnt + i) = sum_i of batch b, (b*2*cnt + cnt + i) = sumsq.
__device__ __forceinline__ void mk_muisd_b(const double* st, int cnt, double M,
                                           float* smu, float* sisd) {
    const int i = threadIdx.x;
    if (i < cnt) {
        double s1 = 0.0, s2 = 0.0;
#pragma unroll
        for (int b = 0; b < B; ++b) {
            s1 += st[S8(b * 2 * cnt + i)];
            s2 += st[S8(b * 2 * cnt + cnt + i)];
        }
        double m = s1 / M;
        double v = s2 / M - m * m;
        smu[i] = (float)m;
        sisd[i] = (float)(1.0 / sqrt(v + 1e-5));
    }
}

// volatile variant for use after grid.sync (bypass stale cache lines)
__device__ __forceinline__ void mk_muisd_v(const double* st, int cnt, double M,
                                           float* smu, float* sisd) {
    const int i = threadIdx.x;
    if (i < cnt) {
        const volatile double* vst = (const volatile double*)st;
        double s1 = 0.0, s2 = 0.0;
#pragma unroll
        for (int b = 0; b < B; ++b) {
            s1 += vst[S8(b * 2 * cnt + i)];
            s2 += vst[S8(b * 2 * cnt + cnt + i)];
        }
        double m = s1 / M;
        double v = s2 / M - m * m;
        smu[i] = (float)m;
        sisd[i] = (float)(1.0 / sqrt(v + 1e-5));
    }
}

struct Feat {
    float cx, cy, cz, e0x, e0y, e0z, e2x, e2y, e2z;
};

__device__ __forceinline__ Feat make_feat(const float* __restrict__ pc,
                                          const int* __restrict__ nbr, int pid) {
    const int b = pid >> 12, n = pid & (N - 1);
    const float* base = pc + (size_t)b * (3 * N);
    Feat f;
    f.cx = base[3 * n];
    f.cy = base[3 * n + 1];
    f.cz = base[3 * n + 2];
    const int jn = nbr[pid];
    float nx = base[3 * jn], ny = base[3 * jn + 1], nz = base[3 * jn + 2];
    f.e0x = nx - f.cx;
    f.e0y = ny - f.cy;
    f.e0z = nz - f.cz;
    f.e2x = ny * f.cz - nz * f.cy;
    f.e2y = nz * f.cx - nx * f.cz;
    f.e2z = nx * f.cy - ny * f.cx;
    return f;
}

__device__ __forceinline__ void l0_channel(const Feat& f, float w0, float w1,
                                           float w2, float u0, float u1, float u2,
                                           float mu, float isd, float g, float bb,
                                           float& x0, float& x1, float& x2) {
    float pSx = w1 * f.cx, pSy = w1 * f.cy, pSz = w1 * f.cz;
    float nS = sqrtf(pSx * pSx + pSy * pSy + pSz * pSz) + EPSF;
    float sS = ((nS - mu) * isd * g + bb) / nS;
    float oSx, oSy, oSz;
    leaky3(pSx, pSy, pSz, u1 * f.cx, u1 * f.cy, u1 * f.cz, sS, oSx, oSy, oSz);
    float px = w0 * f.e0x + w1 * f.cx + w2 * f.e2x;
    float py = w0 * f.e0y + w1 * f.cy + w2 * f.e2y;
    float pz = w0 * f.e0z + w1 * f.cz + w2 * f.e2z;
    float dx = u0 * f.e0x + u1 * f.cx + u2 * f.e2x;
    float dy = u0 * f.e0y + u1 * f.cy + u2 * f.e2y;
    float dz = u0 * f.e0z + u1 * f.cz + u2 * f.e2z;
    float nN = sqrtf(px * px + py * py + pz * pz) + EPSF;
    float sN = ((nN - mu) * isd * g + bb) / nN;
    float oNx, oNy, oNz;
    leaky3(px, py, pz, dx, dy, dz, sN, oNx, oNy, oNz);
    x0 = 0.5f * (oSx + oNx);
    x1 = 0.5f * (oSy + oNy);
    x2 = 0.5f * (oSz + oNz);
}

// ---------------- K1: nearest-other (branch-free scan) + layer0 BN stats -----------
#define QW 8
__global__ __launch_bounds__(256) void k_knn(const float* __restrict__ pc,
                                             const float* __restrict__ Wf0,
                                             int* __restrict__ nbrbest,
                                             double* __restrict__ st0) {
    __shared__ float sx[N], sy[N], sz[N];
    __shared__ float ws0[63], sred[168];
    const int b = blockIdx.x >> 7;
    const int qblk = (blockIdx.x & 127) * 32;
    const float* base = pc + (size_t)b * (N * 3);
    for (int j = threadIdx.x; j < N; j += 256) {
        sx[j] = base[3 * j + 0];
        sy[j] = base[3 * j + 1];
        sz[j] = base[3 * j + 2];
    }
    if (threadIdx.x < 63) ws0[threadIdx.x] = Wf0[threadIdx.x];
    __syncthreads();
    const int wid = threadIdx.x >> 6, lane = threadIdx.x & 63;
    const int q0 = qblk + wid * QW;
    float qx[QW], qy[QW], qz[QW], bv[QW];
    int bi[QW], bq[QW];
#pragma unroll
    for (int q = 0; q < QW; ++q) {
        qx[q] = sx[q0 + q];
        qy[q] = sy[q0 + q];
        qz[q] = sz[q0 + q];
        bv[q] = -3.0e38f;
        bi[q] = 0;
    }
#pragma unroll 4
    for (int ch = 0; ch < N / 64; ++ch) {
        const int j = ch * 64 + lane;
        const float xd = sx[j], yd = sy[j], zd = sz[j];
        const float nr2h = -0.5f * (xd * xd + yd * yd + zd * zd);
#pragma unroll
        for (int q = 0; q < QW; ++q) {
            float pd = fmaf(qx[q], xd, fmaf(qy[q], yd, fmaf(qz[q], zd, nr2h)));
            bool upd = (pd > bv[q]) && (j != q0 + q);
            bv[q] = upd ? pd : bv[q];
            bi[q] = upd ? j : bi[q];
        }
    }
#pragma unroll
    for (int q = 0; q < QW; ++q) {
        float a0v = bv[q], a1v = -3.0e38f;
        int a0i = bi[q], a1i = 0x7fffffff;
#pragma unroll
        for (int m = 1; m < 64; m <<= 1) {
            float b0v = __shfl_xor(a0v, m, 64), b1v = __shfl_xor(a1v, m, 64);
            int b0i = __shfl_xor(a0i, m, 64), b1i = __shfl_xor(a1i, m, 64);
            bool bf = (b0v > a0v) || (b0v == a0v && b0i < a0i);
            float c0v = bf ? a0v : b0v;
            int c0i = bf ? a0i : b0i;
            float c1v = bf ? b1v : a1v;
            int c1i = bf ? b1i : a1i;
            a0v = bf ? b0v : a0v;
            a0i = bf ? b0i : a0i;
            bool cf = (c0v > c1v) || (c0v == c1v && c0i < c1i);
            a1v = cf ? c0v : c1v;
            a1i = cf ? c0i : c1i;
        }
        const int i0 = a0i, i1 = a1i;
        double dxa = (double)qx[q] - (double)sx[i0];
        double dya = (double)qy[q] - (double)sy[i0];
        double dza = (double)qz[q] - (double)sz[i0];
        double d0 = dxa * dxa + dya * dya + dza * dza;
        double dxb = (double)qx[q] - (double)sx[i1];
        double dyb = (double)qy[q] - (double)sy[i1];
        double dzb = (double)qz[q] - (double)sz[i1];
        double d1 = dxb * dxb + dyb * dyb + dzb * dzb;
        bool take1 = (d1 < d0) || (d1 == d0 && i1 < i0);
        int best = take1 ? i1 : i0;
        bq[q] = best;
        if (lane == 0) nbrbest[(size_t)b * N + q0 + q] = best;
    }
    if (lane < 21) {
        float s1 = 0.f, s2 = 0.f;
        const float w0 = ws0[3 * lane], w1 = ws0[3 * lane + 1], w2 = ws0[3 * lane + 2];
#pragma unroll
        for (int q = 0; q < QW; ++q) {
            const int sq = q0 + q, jn = bq[q];
            const float cx = sx[sq], cy = sy[sq], cz = sz[sq];
            const float nx = sx[jn], ny = sy[jn], nz = sz[jn];
            const float e0x = nx - cx, e0y = ny - cy, e0z = nz - cz;
            const float e2x = ny * cz - nz * cy;
            const float e2y = nz * cx - nx * cz;
            const float e2z = nx * cy - ny * cx;
            float pSx = w1 * cx, pSy = w1 * cy, pSz = w1 * cz;
            float nS = sqrtf(pSx * pSx + pSy * pSy + pSz * pSz) + EPSF;
            float px = w0 * e0x + w1 * cx + w2 * e2x;
            float py = w0 * e0y + w1 * cy + w2 * e2y;
            float pz = w0 * e0z + w1 * cz + w2 * e2z;
            float nN = sqrtf(px * px + py * py + pz * pz) + EPSF;
            s1 += nS + nN;
            s2 += nS * nS + nN * nN;
        }
        sred[wid * 42 + lane] = s1;
        sred[wid * 42 + 21 + lane] = s2;
    }
    __syncthreads();
    if (threadIdx.x < 42) {
        float p = sred[threadIdx.x] + sred[42 + threadIdx.x] +
                  sred[84 + threadIdx.x] + sred[126 + threadIdx.x];
        atomicAdd(&st0[S8(b * 42 + threadIdx.x)], (double)p);
    }
}

// ---------------- K2 (primary): cooperative mega-tail, 512 blocks x 2 tiles ---------
// NO register cap: co-residency needs only 2 blocks/CU (VGPR budget 256/wave).
__global__ __launch_bounds__(256) void k_mega(
    const float* __restrict__ pc, const int* __restrict__ nbr,
    const float* __restrict__ Wf0, const float* __restrict__ Wd0,
    const float* __restrict__ g0, const float* __restrict__ b0,
    const float* __restrict__ Wf1, const float* __restrict__ Wd1,
    const float* __restrict__ g1, const float* __restrict__ b1,
    const float* __restrict__ gbn1, const float* __restrict__ bbn1,
    const float* __restrict__ Wf2, const float* __restrict__ Wd2,
    const float* __restrict__ g2, const float* __restrict__ b2,
    const double* __restrict__ st0, double* __restrict__ st1,
    double* __restrict__ stB, double* __restrict__ st2,
    double* __restrict__ acc, float* __restrict__ out) {
    __shared__ float xs[2][63 * 64];
    __shared__ float wf0[63], wd0[63], wf1[441], wd1[441], wf2[63], wd2[63];
    __shared__ float g0s[21], b0s[21], g1s[21], b1s[21], gBs[21], bBs[21], g2s[3], b2s[3];
    __shared__ float mu0[21], isd0[21], mu1[21], isd1[21], muB[21], isdB[21], mu2[3], isd2[3];
    cg::grid_group grid = cg::this_grid();
    const int lane = threadIdx.x & 63, grp = threadIdx.x >> 6;
    const int cbase = grp * 6;

    if (threadIdx.x < 63) {
        wf0[threadIdx.x] = Wf0[threadIdx.x];
        wd0[threadIdx.x] = Wd0[threadIdx.x];
        wf2[threadIdx.x] = Wf2[threadIdx.x];
        wd2[threadIdx.x] = Wd2[threadIdx.x];
    }
    for (int i = threadIdx.x; i < 441; i += 256) {
        wf1[i] = Wf1[i];
        wd1[i] = Wd1[i];
    }
    if (threadIdx.x < 21) {
        g0s[threadIdx.x] = g0[threadIdx.x];
        b0s[threadIdx.x] = b0[threadIdx.x];
        g1s[threadIdx.x] = g1[threadIdx.x];
        b1s[threadIdx.x] = b1[threadIdx.x];
        gBs[threadIdx.x] = gbn1[threadIdx.x];
        bBs[threadIdx.x] = bbn1[threadIdx.x];
    }
    if (threadIdx.x < 3) {
        g2s[threadIdx.x] = g2[threadIdx.x];
        b2s[threadIdx.x] = b2[threadIdx.x];
    }
    mk_muisd_b(st0, 21, (double)NPTS * 2.0, mu0, isd0);
    __syncthreads();

    // ---- Stage A: layer0 apply -> xs[t] ----
    for (int t = 0; t < 2; ++t) {
        const int pid = (blockIdx.x + t * MGB) * 64 + lane;
        Feat f = make_feat(pc, nbr, pid);
#pragma unroll
        for (int k = 0; k < 6; ++k) {
            const int c = cbase + k;
            if (c >= 21) break;
            float x0, x1, x2;
            l0_channel(f, wf0[3 * c], wf0[3 * c + 1], wf0[3 * c + 2],
                       wd0[3 * c], wd0[3 * c + 1], wd0[3 * c + 2],
                       mu0[c], isd0[c], g0s[c], b0s[c], x0, x1, x2);
            xs[t][(3 * c + 0) * 64 + lane] = x0;
            xs[t][(3 * c + 1) * 64 + lane] = x1;
            xs[t][(3 * c + 2) * 64 + lane] = x2;
        }
    }
    __syncthreads();
    // ---- Stage A2: layer1 BN stats ----
    for (int t = 0; t < 2; ++t) {
        const int bb = (blockIdx.x + t * MGB) >> 6;
        float a0[6], a1[6], a2[6];
#pragma unroll
        for (int k = 0; k < 6; ++k) { a0[k] = 0.f; a1[k] = 0.f; a2[k] = 0.f; }
        for (int j = 0; j < 21; ++j) {
            float x0 = xs[t][(3 * j + 0) * 64 + lane];
            float x1 = xs[t][(3 * j + 1) * 64 + lane];
            float x2 = xs[t][(3 * j + 2) * 64 + lane];
#pragma unroll
            for (int k = 0; k < 6; ++k) {
                int cc = cbase + k;
                cc = cc < 21 ? cc : 20;
                float w = wf1[cc * 21 + j];
                a0[k] = fmaf(w, x0, a0[k]);
                a1[k] = fmaf(w, x1, a1[k]);
                a2[k] = fmaf(w, x2, a2[k]);
            }
        }
#pragma unroll
        for (int k = 0; k < 6; ++k) {
            const int c = cbase + k;
            if (c >= 21) break;
            float nn = sqrtf(a0[k] * a0[k] + a1[k] * a1[k] + a2[k] * a2[k]) + EPSF;
            float r1 = waveReduceSum(nn);
            float r2 = waveReduceSum(nn * nn);
            if (lane == 0) {
                atomicAdd(&st1[S8(bb * 42 + c)], (double)r1);
                atomicAdd(&st1[S8(bb * 42 + 21 + c)], (double)r2);
            }
        }
    }
    grid.sync();

    // ---- Stage B: layer1 apply (in LDS) + bn1 stats ----
    mk_muisd_v(st1, 21, (double)NPTS, mu1, isd1);
    __syncthreads();
    for (int t = 0; t < 2; ++t) {
        const int bb = (blockIdx.x + t * MGB) >> 6;
        float p0[6], p1[6], p2[6], q0[6], q1[6], q2[6];
#pragma unroll
        for (int k = 0; k < 6; ++k) {
            p0[k] = 0.f; p1[k] = 0.f; p2[k] = 0.f;
            q0[k] = 0.f; q1[k] = 0.f; q2[k] = 0.f;
        }
        for (int j = 0; j < 21; ++j) {
            float x0 = xs[t][(3 * j + 0) * 64 + lane];
            float x1 = xs[t][(3 * j + 1) * 64 + lane];
            float x2 = xs[t][(3 * j + 2) * 64 + lane];
#pragma unroll
            for (int k = 0; k < 6; ++k) {
                int cc = cbase + k;
                cc = cc < 21 ? cc : 20;
                float w = wf1[cc * 21 + j], u = wd1[cc * 21 + j];
                p0[k] = fmaf(w, x0, p0[k]);
                p1[k] = fmaf(w, x1, p1[k]);
                p2[k] = fmaf(w, x2, p2[k]);
                q0[k] = fmaf(u, x0, q0[k]);
                q1[k] = fmaf(u, x1, q1[k]);
                q2[k] = fmaf(u, x2, q2[k]);
            }
        }
        float sn1[6], sn2[6];
#pragma unroll
        for (int k = 0; k < 6; ++k) {
            int cc = cbase + k;
            cc = cc < 21 ? cc : 20;
            float nn = sqrtf(p0[k] * p0[k] + p1[k] * p1[k] + p2[k] * p2[k]) + EPSF;
            float s = ((nn - mu1[cc]) * isd1[cc] * g1s[cc] + b1s[cc]) / nn;
            float ox, oy, oz;
            leaky3(p0[k], p1[k], p2[k], q0[k], q1[k], q2[k], s, ox, oy, oz);
            p0[k] = ox; p1[k] = oy; p2[k] = oz;
            float on = sqrtf(ox * ox + oy * oy + oz * oz) + EPSF;
            sn1[k] = on;
            sn2[k] = on * on;
        }
        __syncthreads();  // tile-t reads complete before overwrite
#pragma unroll
        for (int k = 0; k < 6; ++k) {
            const int c = cbase + k;
            if (c >= 21) break;
            xs[t][(3 * c + 0) * 64 + lane] = p0[k];
            xs[t][(3 * c + 1) * 64 + lane] = p1[k];
            xs[t][(3 * c + 2) * 64 + lane] = p2[k];
            float r1 = waveReduceSum(sn1[k]);
            float r2 = waveReduceSum(sn2[k]);
            if (lane == 0) {
                atomicAdd(&stB[S8(bb * 42 + c)], (double)r1);
                atomicAdd(&stB[S8(bb * 42 + 21 + c)], (double)r2);
            }
        }
        __syncthreads();
    }
    grid.sync();

    // ---- Stage C: bn1 apply in place + layer2 BN stats ----
    mk_muisd_v(stB, 21, (double)NPTS, muB, isdB);
    __syncthreads();
    for (int t = 0; t < 2; ++t) {
#pragma unroll
        for (int k = 0; k < 6; ++k) {
            const int c = cbase + k;
            if (c >= 21) break;
            float y0 = xs[t][(3 * c + 0) * 64 + lane];
            float y1 = xs[t][(3 * c + 1) * 64 + lane];
            float y2 = xs[t][(3 * c + 2) * 64 + lane];
            float nn = sqrtf(y0 * y0 + y1 * y1 + y2 * y2) + EPSF;
            float sc = ((nn - muB[c]) * isdB[c] * gBs[c] + bBs[c]) / nn;
            xs[t][(3 * c + 0) * 64 + lane] = sc * y0;
            xs[t][(3 * c + 1) * 64 + lane] = sc * y1;
            xs[t][(3 * c + 2) * 64 + lane] = sc * y2;
        }
    }
    __syncthreads();
    if (grp < 3) {
        for (int t = 0; t < 2; ++t) {
            const int bb = (blockIdx.x + t * MGB) >> 6;
            float p0 = 0.f, p1 = 0.f, p2 = 0.f;
            for (int j = 0; j < 21; ++j) {
                float w = wf2[grp * 21 + j];
                p0 = fmaf(w, xs[t][(3 * j + 0) * 64 + lane], p0);
                p1 = fmaf(w, xs[t][(3 * j + 1) * 64 + lane], p1);
                p2 = fmaf(w, xs[t][(3 * j + 2) * 64 + lane], p2);
            }
            float nn = sqrtf(p0 * p0 + p1 * p1 + p2 * p2) + EPSF;
            float r1 = waveReduceSum(nn);
            float r2 = waveReduceSum(nn * nn);
            if (lane == 0) {
                atomicAdd(&st2[S8(bb * 6 + grp)], (double)r1);
                atomicAdd(&st2[S8(bb * 6 + 3 + grp)], (double)r2);
            }
        }
    }
    grid.sync();

    // ---- Stage D: layer2 apply + per-batch reduce ----
    mk_muisd_v(st2, 3, (double)NPTS, mu2, isd2);
    __syncthreads();
    if (grp < 3) {
        for (int t = 0; t < 2; ++t) {
            const int bb = (blockIdx.x + t * MGB) >> 6;
            float p0 = 0.f, p1 = 0.f, p2 = 0.f, d0 = 0.f, d1 = 0.f, d2 = 0.f;
            for (int j = 0; j < 21; ++j) {
                float z0 = xs[t][(3 * j + 0) * 64 + lane];
                float z1 = xs[t][(3 * j + 1) * 64 + lane];
                float z2 = xs[t][(3 * j + 2) * 64 + lane];
                float w = wf2[grp * 21 + j], u = wd2[grp * 21 + j];
                p0 = fmaf(w, z0, p0);
                p1 = fmaf(w, z1, p1);
                p2 = fmaf(w, z2, p2);
                d0 = fmaf(u, z0, d0);
                d1 = fmaf(u, z1, d1);
                d2 = fmaf(u, z2, d2);
            }
            float nn = sqrtf(p0 * p0 + p1 * p1 + p2 * p2) + EPSF;
            float s = ((nn - mu2[grp]) * isd2[grp] * g2s[grp] + b2s[grp]) / nn;
            float ox, oy, oz;
            leaky3(p0, p1, p2, d0, d1, d2, s, ox, oy, oz);
            float rx = waveReduceSum(ox);
            float ry = waveReduceSum(oy);
            float rz = waveReduceSum(oz);
            if (lane == 0) {
                atomicAdd(&acc[S8(bb * 9 + grp * 3 + 0)], (double)rx);
                atomicAdd(&acc[S8(bb * 9 + grp * 3 + 1)], (double)ry);
                atomicAdd(&acc[S8(bb * 9 + grp * 3 + 2)], (double)rz);
            }
        }
    }
    grid.sync();
    if (blockIdx.x == 0 && threadIdx.x < B * 9) {
        const volatile double* va = (const volatile double*)acc;
        out[threadIdx.x] = (float)(va[S8(threadIdx.x)] * (1.0 / (double)N));
    }
}

// ================= FALLBACK PATH (round-10 proven tail, used if coop launch fails) ==
__global__ __launch_bounds__(256) void k_l0st1(
    const float* __restrict__ pc, const int* __restrict__ nbr,
    const float* __restrict__ Wf0, const float* __restrict__ Wd0,
    const float* __restrict__ g0, const float* __restrict__ b0,
    const float* __restrict__ Wf1, const double* __restrict__ st0,
    float* __restrict__ xbuf, double* __restrict__ st1) {
    __shared__ float wf0[63], wd0[63], wf1[441], gg[21], bbs[21], mu[21], isd[21];
    __shared__ float xs[63 * 64];
    if (threadIdx.x < 63) {
        wf0[threadIdx.x] = Wf0[threadIdx.x];
        wd0[threadIdx.x] = Wd0[threadIdx.x];
    }
    for (int i = threadIdx.x; i < 441; i += 256) wf1[i] = Wf1[i];
    if (threadIdx.x < 21) {
        gg[threadIdx.x] = g0[threadIdx.x];
        bbs[threadIdx.x] = b0[threadIdx.x];
    }
    mk_muisd_b(st0, 21, (double)NPTS * 2.0, mu, isd);
    __syncthreads();
    const int lane = threadIdx.x & 63, grp = threadIdx.x >> 6;
    const int pid = blockIdx.x * 64 + lane;
    const int bb = blockIdx.x >> 6;
    Feat f = make_feat(pc, nbr, pid);
    const int cbase = grp * 6;
#pragma unroll
    for (int k = 0; k < 6; ++k) {
        const int c = cbase + k;
        if (c >= 21) break;
        float x0, x1, x2;
        l0_channel(f, wf0[3 * c], wf0[3 * c + 1], wf0[3 * c + 2],
                   wd0[3 * c], wd0[3 * c + 1], wd0[3 * c + 2],
                   mu[c], isd[c], gg[c], bbs[c], x0, x1, x2);
        xs[(3 * c + 0) * 64 + lane] = x0;
        xs[(3 * c + 1) * 64 + lane] = x1;
        xs[(3 * c + 2) * 64 + lane] = x2;
        xbuf[(size_t)(3 * c + 0) * NPTS + pid] = x0;
        xbuf[(size_t)(3 * c + 1) * NPTS + pid] = x1;
        xbuf[(size_t)(3 * c + 2) * NPTS + pid] = x2;
    }
    __syncthreads();
    float xl[63];
#pragma unroll
    for (int ff = 0; ff < 63; ++ff) xl[ff] = xs[ff * 64 + lane];
#pragma unroll
    for (int k = 0; k < 6; ++k) {
        const int c = cbase + k;
        if (c >= 21) break;
        float p0 = 0.f, p1 = 0.f, p2 = 0.f;
#pragma unroll
        for (int j = 0; j < 21; ++j) {
            float w = wf1[c * 21 + j];
            p0 = fmaf(w, xl[3 * j + 0], p0);
            p1 = fmaf(w, xl[3 * j + 1], p1);
            p2 = fmaf(w, xl[3 * j + 2], p2);
        }
        float nn = sqrtf(p0 * p0 + p1 * p1 + p2 * p2) + EPSF;
        float r1 = waveReduceSum(nn);
        float r2 = waveReduceSum(nn * nn);
        if (lane == 0) {
            atomicAdd(&st1[S8(bb * 42 + c)], (double)r1);
            atomicAdd(&st1[S8(bb * 42 + 21 + c)], (double)r2);
        }
    }
}

__global__ __launch_bounds__(256) void k_l1stB(
    float* __restrict__ xbuf, const float* __restrict__ Wf1,
    const float* __restrict__ Wd1, const float* __restrict__ g1,
    const float* __restrict__ b1, const double* __restrict__ st1,
    double* __restrict__ stB) {
    __shared__ float wf1[441], wd1[441], gg[21], bbs[21], mu[21], isd[21];
    for (int i = threadIdx.x; i < 441; i += 256) {
        wf1[i] = Wf1[i];
        wd1[i] = Wd1[i];
    }
    if (threadIdx.x < 21) {
        gg[threadIdx.x] = g1[threadIdx.x];
        bbs[threadIdx.x] = b1[threadIdx.x];
    }
    mk_muisd_b(st1, 21, (double)NPTS, mu, isd);
    __syncthreads();
    const int lane = threadIdx.x & 63, grp = threadIdx.x >> 6;
    const int pid = blockIdx.x * 64 + lane;
    const int bb = blockIdx.x >> 6;
    float xl[63];
#pragma unroll
    for (int ff = 0; ff < 63; ++ff) xl[ff] = xbuf[(size_t)ff * NPTS + pid];
    __syncthreads();
    const int cbase = grp * 6;
#pragma unroll
    for (int k = 0; k < 6; ++k) {
        const int c = cbase + k;
        if (c >= 21) break;
        float p0 = 0.f, p1 = 0.f, p2 = 0.f, d0 = 0.f, d1 = 0.f, d2 = 0.f;
#pragma unroll
        for (int j = 0; j < 21; ++j) {
            float w = wf1[c * 21 + j], u = wd1[c * 21 + j];
            p0 = fmaf(w, xl[3 * j + 0], p0);
            p1 = fmaf(w, xl[3 * j + 1], p1);
            p2 = fmaf(w, xl[3 * j + 2], p2);
            d0 = fmaf(u, xl[3 * j + 0], d0);
            d1 = fmaf(u, xl[3 * j + 1], d1);
            d2 = fmaf(u, xl[3 * j + 2], d2);
        }
        float nn = sqrtf(p0 * p0 + p1 * p1 + p2 * p2) + EPSF;
        float s = ((nn - mu[c]) * isd[c] * gg[c] + bbs[c]) / nn;
        float ox, oy, oz;
        leaky3(p0, p1, p2, d0, d1, d2, s, ox, oy, oz);
        xbuf[(size_t)(3 * c + 0) * NPTS + pid] = ox;
        xbuf[(size_t)(3 * c + 1) * NPTS + pid] = oy;
        xbuf[(size_t)(3 * c + 2) * NPTS + pid] = oz;
        float on = sqrtf(ox * ox + oy * oy + oz * oz) + EPSF;
        float r1 = waveReduceSum(on);
        float r2 = waveReduceSum(on * on);
        if (lane == 0) {
            atomicAdd(&stB[S8(bb * 42 + c)], (double)r1);
            atomicAdd(&stB[S8(bb * 42 + 21 + c)], (double)r2);
        }
    }
}

__global__ __launch_bounds__(256) void k_bn1st2(
    const float* __restrict__ xbuf, const float* __restrict__ gbn,
    const float* __restrict__ bbn, const float* __restrict__ Wf2,
    const double* __restrict__ stB, double* __restrict__ st2) {
    __shared__ float wf2[63], gg[21], bbs[21], mu[21], isd[21];
    __shared__ float zs[63 * 64];
    if (threadIdx.x < 63) wf2[threadIdx.x] = Wf2[threadIdx.x];
    if (threadIdx.x < 21) {
        gg[threadIdx.x] = gbn[threadIdx.x];
        bbs[threadIdx.x] = bbn[threadIdx.x];
    }
    mk_muisd_b(stB, 21, (double)NPTS, mu, isd);
    __syncthreads();
    const int lane = threadIdx.x & 63, grp = threadIdx.x >> 6;
    const int pid = blockIdx.x * 64 + lane;
    const int bb = blockIdx.x >> 6;
    const int cbase = grp * 6;
#pragma unroll
    for (int k = 0; k < 6; ++k) {
        const int c = cbase + k;
        if (c >= 21) break;
        float y0 = xbuf[(size_t)(3 * c + 0) * NPTS + pid];
        float y1 = xbuf[(size_t)(3 * c + 1) * NPTS + pid];
        float y2 = xbuf[(size_t)(3 * c + 2) * NPTS + pid];
        float nn = sqrtf(y0 * y0 + y1 * y1 + y2 * y2) + EPSF;
        float sc = ((nn - mu[c]) * isd[c] * gg[c] + bbs[c]) / nn;
        zs[(3 * c + 0) * 64 + lane] = sc * y0;
        zs[(3 * c + 1) * 64 + lane] = sc * y1;
        zs[(3 * c + 2) * 64 + lane] = sc * y2;
    }
    __syncthreads();
    if (grp < 3) {
        float p0 = 0.f, p1 = 0.f, p2 = 0.f;
#pragma unroll
        for (int j = 0; j < 21; ++j) {
            float w = wf2[grp * 21 + j];
            p0 = fmaf(w, zs[(3 * j + 0) * 64 + lane], p0);
            p1 = fmaf(w, zs[(3 * j + 1) * 64 + lane], p1);
            p2 = fmaf(w, zs[(3 * j + 2) * 64 + lane], p2);
        }
        float nn = sqrtf(p0 * p0 + p1 * p1 + p2 * p2) + EPSF;
        float r1 = waveReduceSum(nn);
        float r2 = waveReduceSum(nn * nn);
        if (lane == 0) {
            atomicAdd(&st2[S8(bb * 6 + grp)], (double)r1);
            atomicAdd(&st2[S8(bb * 6 + 3 + grp)], (double)r2);
        }
    }
}

__global__ __launch_bounds__(256) void k_acc(
    const float* __restrict__ xbuf, const float* __restrict__ gbn,
    const float* __restrict__ bbn, const float* __restrict__ Wf2,
    const float* __restrict__ Wd2, const float* __restrict__ g2,
    const float* __restrict__ b2, const double* __restrict__ stB,
    const double* __restrict__ st2, double* __restrict__ acc) {
    __shared__ float wf2[63], wd2[63], gg[3], bbs[3];
    __shared__ float muB[21], isdB[21], gB[21], bB[21], mu2[3], isd2[3];
    if (threadIdx.x < 63) {
        wf2[threadIdx.x] = Wf2[threadIdx.x];
        wd2[threadIdx.x] = Wd2[threadIdx.x];
    }
    if (threadIdx.x < 21) {
        gB[threadIdx.x] = gbn[threadIdx.x];
        bB[threadIdx.x] = bbn[threadIdx.x];
    }
    if (threadIdx.x < 3) {
        gg[threadIdx.x] = g2[threadIdx.x];
        bbs[threadIdx.x] = b2[threadIdx.x];
    }
    mk_muisd_b(stB, 21, (double)NPTS, muB, isdB);
    mk_muisd_b(st2, 3, (double)NPTS, mu2, isd2);
    __syncthreads();
    const int lane = threadIdx.x & 63, grp = threadIdx.x >> 6;
    if (grp >= 3) return;
    const int pid = blockIdx.x * 64 + lane;
    const int bb = pid >> 12;
    float p0 = 0.f, p1 = 0.f, p2 = 0.f, d0 = 0.f, d1 = 0.f, d2 = 0.f;
#pragma unroll
    for (int j = 0; j < 21; ++j) {
        float y0 = xbuf[(size_t)(3 * j + 0) * NPTS + pid];
        float y1 = xbuf[(size_t)(3 * j + 1) * NPTS + pid];
        float y2 = xbuf[(size_t)(3 * j + 2) * NPTS + pid];
        float nn = sqrtf(y0 * y0 + y1 * y1 + y2 * y2) + EPSF;
        float sc = ((nn - muB[j]) * isdB[j] * gB[j] + bB[j]) / nn;
        float z0 = sc * y0, z1 = sc * y1, z2 = sc * y2;
        float w = wf2[grp * 21 + j], u = wd2[grp * 21 + j];
        p0 = fmaf(w, z0, p0);
        p1 = fmaf(w, z1, p1);
        p2 = fmaf(w, z2, p2);
        d0 = fmaf(u, z0, d0);
        d1 = fmaf(u, z1, d1);
        d2 = fmaf(u, z2, d2);
    }
    float nn = sqrtf(p0 * p0 + p1 * p1 + p2 * p2) + EPSF;
    float s = ((nn - mu2[grp]) * isd2[grp] * gg[grp] + bbs[grp]) / nn;
    float ox, oy, oz;
    leaky3(p0, p1, p2, d0, d1, d2, s, ox, oy, oz);
    float rx = waveReduceSum(ox);
    float ry = waveReduceSum(oy);
    float rz = waveReduceSum(oz);
    if (lane == 0) {
        atomicAdd(&acc[S8(bb * 9 + grp * 3 + 0)], (double)rx);
        atomicAdd(&acc[S8(bb * 9 + grp * 3 + 1)], (double)ry);
        atomicAdd(&acc[S8(bb * 9 + grp * 3 + 2)], (double)rz);
    }
}

__global__ void k_fin(const double* __restrict__ acc, float* __restrict__ out) {
    if (threadIdx.x < B * 9)
        out[threadIdx.x] = (float)(acc[S8(threadIdx.x)] * (1.0 / (double)N));
}

extern "C" void kernel_launch(void* const* d_in, const int* in_sizes, int n_in,
                              void* d_out, int out_size, void* d_ws, size_t ws_size,
                              hipStream_t stream) {
    const float* pc = (const float*)d_in[0];
    const float* Wf0 = (const float*)d_in[1];
    const float* Wd0 = (const float*)d_in[2];
    const float* g0 = (const float*)d_in[3];
    const float* b0 = (const float*)d_in[4];
    const float* Wf1 = (const float*)d_in[5];
    const float* Wd1 = (const float*)d_in[6];
    const float* g1 = (const float*)d_in[7];
    const float* b1 = (const float*)d_in[8];
    const float* gbn1 = (const float*)d_in[9];
    const float* bbn1 = (const float*)d_in[10];
    const float* Wf2 = (const float*)d_in[11];
    const float* Wd2 = (const float*)d_in[12];
    const float* g2 = (const float*)d_in[13];
    const float* b2 = (const float*)d_in[14];
    float* out = (float*)d_out;

    char* ws = (char*)d_ws;
    double* gws = (double*)ws;
    double* st0 = gws;                // slots [0, 672)
    double* st1 = gws + S8(672);      // [672, 1344)
    double* stB = gws + S8(1344);     // [1344, 2016)
    double* st2 = gws + S8(2016);     // [2016, 2112)
    double* acc = gws + S8(2112);     // [2112, 2256)  -> 144384 B
    int* nbrbest = (int*)(ws + 262144);   // 256 KB
    float* xbuf = (float*)(ws + 524288);  // 63*NPTS f32 = 16.5 MB (fallback only)

    hipMemsetAsync(d_ws, 0, 144384, stream);

    k_knn<<<NBK, 256, 0, stream>>>(pc, Wf0, nbrbest, st0);

    const int* nbrc = nbrbest;
    const double* st0c = st0;
    void* args[] = {(void*)&pc, (void*)&nbrc,
                    (void*)&Wf0, (void*)&Wd0, (void*)&g0, (void*)&b0,
                    (void*)&Wf1, (void*)&Wd1, (void*)&g1, (void*)&b1,
                    (void*)&gbn1, (void*)&bbn1,
                    (void*)&Wf2, (void*)&Wd2, (void*)&g2, (void*)&b2,
                    (void*)&st0c, (void*)&st1, (void*)&stB, (void*)&st2,
                    (void*)&acc, (void*)&out};
    hipError_t e = hipLaunchCooperativeKernel((void*)k_mega, dim3(MGB), dim3(256),
                                              args, 0, stream);
    if (e != hipSuccess) {
        // fallback: proven round-10 multi-kernel tail
        k_l0st1<<<NBT, 256, 0, stream>>>(pc, nbrbest, Wf0, Wd0, g0, b0, Wf1, st0,
                                         xbuf, st1);
        k_l1stB<<<NBT, 256, 0, stream>>>(xbuf, Wf1, Wd1, g1, b1, st1, stB);
        k_bn1st2<<<NBT, 256, 0, stream>>>(xbuf, gbn1, bbn1, Wf2, stB, st2);
        k_acc<<<NBT, 256, 0, stream>>>(xbuf, gbn1, bbn1, Wf2, Wd2, g2, b2, stB,
                                       st2, acc);
        k_fin<<<1, 256, 0, stream>>>(acc, out);
    }
}